// Round 3
// baseline (687.048 us; speedup 1.0000x reference)
//
#include <hip/hip_runtime.h>

// GraphConv autoencoder forward. Plan:
//   preprocess: deg (atomic int) -> dinv -> scan -> CSR fill (packed int2 {src, norm_bits})
//   6 GCN layers with width-minimized aggregation (aggregate on narrow side):
//     L1: h=x@W1 (N,16)           -> AGG16 +b1,relu -> x1
//     L2: AGG16(x1)               -> @W2 +b2,relu   -> x2 (N,32)
//     L3: AGG32(x2)               -> @W3 +b3,relu   -> x3 (N,64)
//     z = x3@We+be; d = relu(z@Wd+bd)
//     dL1: h=[d|x2]@dW1 (N,32)    -> AGG32 +db1,relu -> y1
//     dL2: h=[y1|x1]@dW2 (N,16)   -> AGG16 +db2,relu -> y2
//     dL3: AGG16(y2)              -> @dW3 +db3,tanh  -> out (N,128)
// NOTE: harness passes integer inputs as int32 (edge_index is const int*, NOT int64).

#define CDIV(a,b) (((a)+(b)-1)/(b))

__global__ void k_init(int* degi, int* cnt, int n) {
  int i = blockIdx.x * blockDim.x + threadIdx.x;
  if (i < n) { degi[i] = 1; cnt[i] = 0; }  // deg includes self-loop
}

__global__ void k_count(const int* __restrict__ dst, int* __restrict__ degi, int e) {
  int i = blockIdx.x * blockDim.x + threadIdx.x;
  if (i < e) atomicAdd(&degi[dst[i]], 1);
}

__global__ void k_dinv(const int* __restrict__ degi, float* __restrict__ dinv, int n) {
  int i = blockIdx.x * blockDim.x + threadIdx.x;
  if (i < n) dinv[i] = rsqrtf((float)degi[i]);  // deg >= 1 always
}

// inclusive scan within 1024-elem blocks; rowptr1 = rowptr+1
__global__ void k_scan_block(const int* __restrict__ in, int* __restrict__ rowptr1,
                             int* __restrict__ bsums, int n) {
  __shared__ int tmp[1024];
  int i = blockIdx.x * 1024 + threadIdx.x;
  tmp[threadIdx.x] = (i < n) ? in[i] : 0;
  __syncthreads();
  for (int off = 1; off < 1024; off <<= 1) {
    int t = (threadIdx.x >= off) ? tmp[threadIdx.x - off] : 0;
    __syncthreads();
    tmp[threadIdx.x] += t;
    __syncthreads();
  }
  if (i < n) rowptr1[i] = tmp[threadIdx.x];
  if (threadIdx.x == 1023) bsums[blockIdx.x] = tmp[1023];
}

__global__ void k_scan_sums(int* bsums, int nb) {
  if (threadIdx.x == 0) {
    int run = 0;
    for (int i = 0; i < nb; ++i) { int v = bsums[i]; bsums[i] = run; run += v; }
  }
}

__global__ void k_rowptr_fix(int* rowptr, const int* __restrict__ bsums, int n) {
  int i = blockIdx.x * blockDim.x + threadIdx.x;
  if (i < n) rowptr[i + 1] += bsums[i >> 10];
  if (i == 0) rowptr[0] = 0;
}

__global__ void k_fill(const int* __restrict__ esrc, const int* __restrict__ edst,
                       const float* __restrict__ dinv, const int* __restrict__ rowptr,
                       int* __restrict__ cnt, int2* __restrict__ csr, int e, int n) {
  int i = blockIdx.x * blockDim.x + threadIdx.x;
  if (i >= e + n) return;
  int s, d;
  if (i < e) { s = esrc[i]; d = edst[i]; }
  else       { s = d = i - e; }                  // self-loop entries
  int slot = rowptr[d] + atomicAdd(&cnt[d], 1);
  csr[slot] = make_int2(s, __float_as_int(dinv[s] * dinv[d]));
}

// Aggregation: W/4 lanes per node, float4 per lane. CSR gather, no atomics.
template <int W, int ACT>
__global__ __launch_bounds__(256) void k_agg(const float* __restrict__ h,
                                             const int2* __restrict__ csr,
                                             const int* __restrict__ rowptr,
                                             const float* __restrict__ bias,
                                             float* __restrict__ out, int n) {
  constexpr int L = W / 4;
  int g = blockIdx.x * (256 / L) + threadIdx.x / L;
  if (g >= n) return;
  int lane = threadIdx.x & (L - 1);
  int beg = rowptr[g], end = rowptr[g + 1];
  float4 acc = make_float4(0.f, 0.f, 0.f, 0.f);
  for (int j = beg; j < end; ++j) {
    int2 en = csr[j];
    float wt = __int_as_float(en.y);
    float4 hv = *reinterpret_cast<const float4*>(h + (long long)en.x * W + lane * 4);
    acc.x = fmaf(wt, hv.x, acc.x);
    acc.y = fmaf(wt, hv.y, acc.y);
    acc.z = fmaf(wt, hv.z, acc.z);
    acc.w = fmaf(wt, hv.w, acc.w);
  }
  if (bias) {
    float4 b = *reinterpret_cast<const float4*>(bias + lane * 4);
    acc.x += b.x; acc.y += b.y; acc.z += b.z; acc.w += b.w;
  }
  if (ACT == 1) {
    acc.x = fmaxf(acc.x, 0.f); acc.y = fmaxf(acc.y, 0.f);
    acc.z = fmaxf(acc.z, 0.f); acc.w = fmaxf(acc.w, 0.f);
  }
  *reinterpret_cast<float4*>(out + (long long)g * W + lane * 4) = acc;
}

// Small GEMM: out[n,M] = [A0|A1] @ Wt[K0+K1, M] (+bias)(+act). W staged in LDS.
// One thread computes 4 output cols of one row. ACT: 0=none 1=relu 2=tanh.
template <int ACT>
__global__ __launch_bounds__(256) void k_gemm(const float* __restrict__ A0, int K0,
                                              const float* __restrict__ A1, int K1,
                                              const float* __restrict__ Wt,
                                              const float* __restrict__ bias,
                                              float* __restrict__ out, int n, int M) {
  extern __shared__ float sW[];
  const int K = K0 + K1;
  for (int i = threadIdx.x; i < K * M; i += blockDim.x) sW[i] = Wt[i];
  __syncthreads();
  const int mv = M >> 2;
  long long idx = (long long)blockIdx.x * blockDim.x + threadIdx.x;
  if (idx >= (long long)n * mv) return;
  int row = (int)(idx / mv);
  int c4 = (int)(idx % mv) * 4;
  float4 acc = make_float4(0.f, 0.f, 0.f, 0.f);
  const float* a0 = A0 + (long long)row * K0;
  for (int k = 0; k < K0; ++k) {
    float a = a0[k];
    float4 w = *reinterpret_cast<const float4*>(&sW[k * M + c4]);
    acc.x = fmaf(a, w.x, acc.x); acc.y = fmaf(a, w.y, acc.y);
    acc.z = fmaf(a, w.z, acc.z); acc.w = fmaf(a, w.w, acc.w);
  }
  if (A1) {
    const float* a1 = A1 + (long long)row * K1;
    for (int k = 0; k < K1; ++k) {
      float a = a1[k];
      float4 w = *reinterpret_cast<const float4*>(&sW[(K0 + k) * M + c4]);
      acc.x = fmaf(a, w.x, acc.x); acc.y = fmaf(a, w.y, acc.y);
      acc.z = fmaf(a, w.z, acc.z); acc.w = fmaf(a, w.w, acc.w);
    }
  }
  if (bias) {
    float4 b = *reinterpret_cast<const float4*>(bias + c4);
    acc.x += b.x; acc.y += b.y; acc.z += b.z; acc.w += b.w;
  }
  if (ACT == 1) {
    acc.x = fmaxf(acc.x, 0.f); acc.y = fmaxf(acc.y, 0.f);
    acc.z = fmaxf(acc.z, 0.f); acc.w = fmaxf(acc.w, 0.f);
  } else if (ACT == 2) {
    acc.x = tanhf(acc.x); acc.y = tanhf(acc.y);
    acc.z = tanhf(acc.z); acc.w = tanhf(acc.w);
  }
  *reinterpret_cast<float4*>(out + (long long)row * M + c4) = acc;
}

extern "C" void kernel_launch(void* const* d_in, const int* in_sizes, int n_in,
                              void* d_out, int out_size, void* d_ws, size_t ws_size,
                              hipStream_t stream) {
  const float* x  = (const float*)d_in[0];
  const int*   ei = (const int*)d_in[1];          // int32 (harness converts int64)
  const float *W1 = (const float*)d_in[2],  *b1  = (const float*)d_in[3];
  const float *W2 = (const float*)d_in[4],  *b2  = (const float*)d_in[5];
  const float *W3 = (const float*)d_in[6],  *b3  = (const float*)d_in[7];
  const float *We = (const float*)d_in[8],  *be  = (const float*)d_in[9];
  const float *Wd = (const float*)d_in[10], *bd  = (const float*)d_in[11];
  const float *dW1 = (const float*)d_in[12], *db1 = (const float*)d_in[13];
  const float *dW2 = (const float*)d_in[14], *db2 = (const float*)d_in[15];
  const float *dW3 = (const float*)d_in[16], *db3 = (const float*)d_in[17];
  float* out = (float*)d_out;

  const int C = 128;
  const int n = in_sizes[0] / C;
  const int e = in_sizes[1] / 2;
  const int* e_src = ei;
  const int* e_dst = ei + e;

  // workspace carve-up (~86 MB total)
  char* p = (char*)d_ws;
  auto alloc = [&](size_t bytes) -> void* {
    void* r = (void*)p;
    p += (bytes + 255) & ~(size_t)255;
    return r;
  };
  int*   degi   = (int*)alloc((size_t)n * 4);
  int*   cnt    = (int*)alloc((size_t)n * 4);
  int*   rowptr = (int*)alloc(((size_t)n + 1) * 4);
  int*   bsums  = (int*)alloc(1024 * 4);
  float* dinv   = (float*)alloc((size_t)n * 4);
  int2*  csr    = (int2*)alloc((size_t)(e + n) * 8);
  float* x1   = (float*)alloc((size_t)n * 16 * 4);
  float* x2   = (float*)alloc((size_t)n * 32 * 4);
  float* bufA = (float*)alloc((size_t)n * 32 * 4);  // agg/gemm scratch (<=32 wide)
  float* bufB = (float*)alloc((size_t)n * 64 * 4);  // x3 then d
  float* bufC = (float*)alloc((size_t)n * 32 * 4);  // z then y1 then y2

  const int B = 256;
  // ---- preprocessing: degrees, dinv, rowptr scan, CSR fill ----
  k_init<<<CDIV(n, B), B, 0, stream>>>(degi, cnt, n);
  k_count<<<CDIV(e, B), B, 0, stream>>>(e_dst, degi, e);
  k_dinv<<<CDIV(n, B), B, 0, stream>>>(degi, dinv, n);
  int nb = CDIV(n, 1024);
  k_scan_block<<<nb, 1024, 0, stream>>>(degi, rowptr + 1, bsums, n);
  k_scan_sums<<<1, 64, 0, stream>>>(bsums, nb);
  k_rowptr_fix<<<CDIV(n, B), B, 0, stream>>>(rowptr, bsums, n);
  k_fill<<<CDIV(e + n, B), B, 0, stream>>>(e_src, e_dst, dinv, rowptr, cnt, csr, e, n);

  // ---- encoder ----
  // L1 (transform-first, agg width 16): h1 = x@W1 ; x1 = relu(AGG(h1)+b1)
  k_gemm<0><<<(int)CDIV((long long)n * 4, B), B, 128 * 16 * 4, stream>>>(
      x, 128, nullptr, 0, W1, nullptr, bufA, n, 16);
  k_agg<16, 1><<<CDIV(n, 64), B, 0, stream>>>(bufA, csr, rowptr, b1, x1, n);
  // L2 (scatter-first, agg width 16): x2 = relu(AGG(x1)@W2+b2)
  k_agg<16, 0><<<CDIV(n, 64), B, 0, stream>>>(x1, csr, rowptr, nullptr, bufA, n);
  k_gemm<1><<<(int)CDIV((long long)n * 8, B), B, 16 * 32 * 4, stream>>>(
      bufA, 16, nullptr, 0, W2, b2, x2, n, 32);
  // L3 (scatter-first, agg width 32): x3 = relu(AGG(x2)@W3+b3)
  k_agg<32, 0><<<CDIV(n, 32), B, 0, stream>>>(x2, csr, rowptr, nullptr, bufA, n);
  k_gemm<1><<<(int)CDIV((long long)n * 16, B), B, 32 * 64 * 4, stream>>>(
      bufA, 32, nullptr, 0, W3, b3, bufB, n, 64);

  // ---- latent ----
  // z = x3@We+be ; d = relu(z@Wd+bd)
  k_gemm<0><<<(int)CDIV((long long)n * 8, B), B, 64 * 32 * 4, stream>>>(
      bufB, 64, nullptr, 0, We, be, bufC, n, 32);
  k_gemm<1><<<(int)CDIV((long long)n * 16, B), B, 32 * 64 * 4, stream>>>(
      bufC, 32, nullptr, 0, Wd, bd, bufB, n, 64);

  // ---- decoder ----
  // dL1 (transform-first, agg width 32): h6 = [d|x2]@dW1 ; y1 = relu(AGG(h6)+db1)
  k_gemm<0><<<(int)CDIV((long long)n * 8, B), B, 96 * 32 * 4, stream>>>(
      bufB, 64, x2, 32, dW1, nullptr, bufA, n, 32);
  k_agg<32, 1><<<CDIV(n, 32), B, 0, stream>>>(bufA, csr, rowptr, db1, bufC, n);
  // dL2 (transform-first, agg width 16): h7 = [y1|x1]@dW2 ; y2 = relu(AGG(h7)+db2)
  k_gemm<0><<<(int)CDIV((long long)n * 4, B), B, 48 * 16 * 4, stream>>>(
      bufC, 32, x1, 16, dW2, nullptr, bufA, n, 16);
  k_agg<16, 1><<<CDIV(n, 64), B, 0, stream>>>(bufA, csr, rowptr, db2, bufC, n);
  // dL3 (scatter-first, agg width 16): out = tanh(AGG(y2)@dW3+db3)
  k_agg<16, 0><<<CDIV(n, 64), B, 0, stream>>>(bufC, csr, rowptr, nullptr, bufA, n);
  k_gemm<2><<<(int)CDIV((long long)n * 32, B), B, 16 * 128 * 4, stream>>>(
      bufA, 16, nullptr, 0, dW3, db3, out, n, 128);
}